// Round 6
// baseline (1588.474 us; speedup 1.0000x reference)
//
#include <hip/hip_runtime.h>
#include <hip/hip_bf16.h>
#include <cfloat>
#include <type_traits>

// Problem constants
#define BB 8
#define TT 2048
#define CC 512
#define NNODE 1024

#define GAP_THRESH 2e-3f  // f32-sim trust margin (~50x worst-case f32 GEMM err)

// ---------------------------------------------------------------------------
// Order-preserving f32 <-> u32 key
// ---------------------------------------------------------------------------
__device__ __forceinline__ unsigned fkey(float v) {
  unsigned u = __float_as_uint(v);
  return (u & 0x80000000u) ? ~u : (u | 0x80000000u);
}
__device__ __forceinline__ float fdec(unsigned k) {
  unsigned u = (k & 0x80000000u) ? (k & 0x7FFFFFFFu) : ~k;
  return __uint_as_float(u);
}

// ---------------------------------------------------------------------------
// f32 tiled GEMM (value path): C[m,n] = alpha*sum_k A[m,k]*B(k,n) (+bias)
// 64x64 tile, BK=16, 256 threads, 4x4 microtile.
// ---------------------------------------------------------------------------
template <int BIAS_MODE, bool TRANS_B, bool OUT_BF16>
__global__ __launch_bounds__(256) void gemm_kernel(
    const float* __restrict__ A, const float* __restrict__ Bm,
    void* __restrict__ Cp, const float* __restrict__ bias,
    int M, int N, int K, int lda, int ldb, int ldc,
    long long strideA, long long strideB, long long strideC, float alpha) {
  __shared__ float As[16][65];
  __shared__ float Bs[16][65];

  const int b = blockIdx.z;
  A += (long long)b * strideA;
  Bm += (long long)b * strideB;

  const int m0 = blockIdx.y * 64;
  const int n0 = blockIdx.x * 64;
  const int tid = threadIdx.x;
  const int tx = tid & 15;
  const int ty = tid >> 4;

  float acc[4][4] = {};

  for (int k0 = 0; k0 < K; k0 += 16) {
#pragma unroll
    for (int i = 0; i < 4; ++i) {
      int idx = tid + i * 256;
      int am = idx >> 4, ak = idx & 15;
      As[ak][am] = A[(long long)(m0 + am) * lda + (k0 + ak)];
    }
    if (!TRANS_B) {
#pragma unroll
      for (int i = 0; i < 4; ++i) {
        int idx = tid + i * 256;
        int bn = idx & 63, bk = idx >> 6;
        Bs[bk][bn] = Bm[(long long)(k0 + bk) * ldb + (n0 + bn)];
      }
    } else {
#pragma unroll
      for (int i = 0; i < 4; ++i) {
        int idx = tid + i * 256;
        int bk = idx & 15, bn = idx >> 4;
        Bs[bk][bn] = Bm[(long long)(n0 + bn) * ldb + (k0 + bk)];
      }
    }
    __syncthreads();

#pragma unroll
    for (int k = 0; k < 16; ++k) {
      float a[4], bb[4];
#pragma unroll
      for (int i = 0; i < 4; ++i) a[i] = As[k][ty + i * 16];
#pragma unroll
      for (int j = 0; j < 4; ++j) bb[j] = Bs[k][tx + j * 16];
#pragma unroll
      for (int i = 0; i < 4; ++i)
#pragma unroll
        for (int j = 0; j < 4; ++j) acc[i][j] = fmaf(a[i], bb[j], acc[i][j]);
    }
    __syncthreads();
  }

#pragma unroll
  for (int i = 0; i < 4; ++i) {
    int m = m0 + ty + i * 16;
#pragma unroll
    for (int j = 0; j < 4; ++j) {
      int n = n0 + tx + j * 16;
      float v = acc[i][j] * alpha;
      if (BIAS_MODE == 1) v += bias[m];
      if (BIAS_MODE == 2) v += bias[n];
      long long off = strideC * b + (long long)m * ldc + n;
      if (OUT_BF16)
        ((__hip_bfloat16*)Cp)[off] = __float2bfloat16(v);
      else
        ((float*)Cp)[off] = v;
    }
  }
}

// ---------------------------------------------------------------------------
// f64-accumulate GEMM with f64-STAGED LDS (decision path: q, k).
// Converts f32->f64 once per tile element at stage time; inner loop is pure
// f64 FMA + b64 LDS reads (no per-FMA cvt).
// ---------------------------------------------------------------------------
template <int BIAS_MODE, bool TRANS_B>
__global__ __launch_bounds__(256) void gemm_f64_kernel(
    const float* __restrict__ A, const float* __restrict__ Bm,
    float* __restrict__ Cp, const float* __restrict__ bias,
    int M, int N, int K, int lda, int ldb, int ldc,
    long long strideA, long long strideB, long long strideC, float alpha) {
  __shared__ double As[16][65];
  __shared__ double Bs[16][65];

  const int b = blockIdx.z;
  A += (long long)b * strideA;
  Bm += (long long)b * strideB;

  const int m0 = blockIdx.y * 64;
  const int n0 = blockIdx.x * 64;
  const int tid = threadIdx.x;
  const int tx = tid & 15;
  const int ty = tid >> 4;

  double acc[4][4] = {};

  for (int k0 = 0; k0 < K; k0 += 16) {
#pragma unroll
    for (int i = 0; i < 4; ++i) {
      int idx = tid + i * 256;
      int am = idx >> 4, ak = idx & 15;
      As[ak][am] = (double)A[(long long)(m0 + am) * lda + (k0 + ak)];
    }
    if (!TRANS_B) {
#pragma unroll
      for (int i = 0; i < 4; ++i) {
        int idx = tid + i * 256;
        int bn = idx & 63, bk = idx >> 6;
        Bs[bk][bn] = (double)Bm[(long long)(k0 + bk) * ldb + (n0 + bn)];
      }
    } else {
#pragma unroll
      for (int i = 0; i < 4; ++i) {
        int idx = tid + i * 256;
        int bk = idx & 15, bn = idx >> 4;
        Bs[bk][bn] = (double)Bm[(long long)(n0 + bn) * ldb + (k0 + bk)];
      }
    }
    __syncthreads();

#pragma unroll
    for (int k = 0; k < 16; ++k) {
      double a[4], bb[4];
#pragma unroll
      for (int i = 0; i < 4; ++i) a[i] = As[k][ty + i * 16];
#pragma unroll
      for (int j = 0; j < 4; ++j) bb[j] = Bs[k][tx + j * 16];
#pragma unroll
      for (int i = 0; i < 4; ++i)
#pragma unroll
        for (int j = 0; j < 4; ++j) acc[i][j] = fma(a[i], bb[j], acc[i][j]);
    }
    __syncthreads();
  }

#pragma unroll
  for (int i = 0; i < 4; ++i) {
    int m = m0 + ty + i * 16;
#pragma unroll
    for (int j = 0; j < 4; ++j) {
      int n = n0 + tx + j * 16;
      float v = (float)(acc[i][j] * (double)alpha);
      if (BIAS_MODE == 1) v += bias[m];
      if (BIAS_MODE == 2) v += bias[n];
      Cp[strideC * b + (long long)m * ldc + n] = v;
    }
  }
}

__global__ __launch_bounds__(256) void fill_zero(unsigned* __restrict__ p, long long n) {
  long long i = (long long)blockIdx.x * 256 + threadIdx.x;
  long long stride = (long long)gridDim.x * 256;
  for (; i < n; i += stride) p[i] = 0u;
}

// ---------------------------------------------------------------------------
// sim in f32 + per-block per-token top-2 candidates.
// cand1/cand2[bt*16 + nblock] = (fkey(sim)<<32)|node for block-local top1/top2.
// ---------------------------------------------------------------------------
__global__ __launch_bounds__(256) void sim_top2_kernel(
    const float* __restrict__ q, const float* __restrict__ k,
    unsigned long long* __restrict__ cand1, unsigned long long* __restrict__ cand2) {
  __shared__ float As[16][65];  // q tile: [kk][node]
  __shared__ float Bs[16][65];  // k tile: [kk][token]
  __shared__ unsigned long long c1[64], c2[64];

  const int b = blockIdx.z;
  const float* A = q + (size_t)b * NNODE * CC;
  const float* Bm = k + (size_t)b * TT * CC;
  const int n0 = blockIdx.y * 64;
  const int t0 = blockIdx.x * 64;
  const int tid = threadIdx.x;
  const int tx = tid & 15;
  const int ty = tid >> 4;

  float acc[4][4] = {};

  for (int k0 = 0; k0 < CC; k0 += 16) {
#pragma unroll
    for (int i = 0; i < 4; ++i) {
      int idx = tid + i * 256;
      int am = idx >> 4, ak = idx & 15;
      As[ak][am] = A[(size_t)(n0 + am) * CC + (k0 + ak)];
    }
#pragma unroll
    for (int i = 0; i < 4; ++i) {
      int idx = tid + i * 256;
      int bk = idx & 15, bn = idx >> 4;
      Bs[bk][bn] = Bm[(size_t)(t0 + bn) * CC + (k0 + bk)];
    }
    __syncthreads();
#pragma unroll
    for (int kk = 0; kk < 16; ++kk) {
      float a[4], bb[4];
#pragma unroll
      for (int i = 0; i < 4; ++i) a[i] = As[kk][ty + i * 16];
#pragma unroll
      for (int j = 0; j < 4; ++j) bb[j] = Bs[kk][tx + j * 16];
#pragma unroll
      for (int i = 0; i < 4; ++i)
#pragma unroll
        for (int j = 0; j < 4; ++j) acc[i][j] = fmaf(a[i], bb[j], acc[i][j]);
    }
    __syncthreads();
  }

  if (tid < 64) { c1[tid] = 0ULL; c2[tid] = 0ULL; }
  __syncthreads();

  const float scl = 0.04419417382415922f;
  unsigned long long pk[4][4];
#pragma unroll
  for (int j = 0; j < 4; ++j) {
    int col = tx + j * 16;
#pragma unroll
    for (int i = 0; i < 4; ++i) {
      float v = acc[i][j] * scl;
      pk[i][j] = ((unsigned long long)fkey(v) << 32) | (unsigned)(n0 + ty + i * 16);
    }
    unsigned long long m = pk[0][j];
#pragma unroll
    for (int i = 1; i < 4; ++i) m = (pk[i][j] > m) ? pk[i][j] : m;
    atomicMax(&c1[col], m);
  }
  __syncthreads();
#pragma unroll
  for (int j = 0; j < 4; ++j) {
    int col = tx + j * 16;
    unsigned win = (unsigned)c1[col];
    unsigned long long m = 0ULL;
#pragma unroll
    for (int i = 0; i < 4; ++i)
      if ((unsigned)pk[i][j] != win && pk[i][j] > m) m = pk[i][j];
    if (m) atomicMax(&c2[col], m);
  }
  __syncthreads();
  if (tid < 64) {
    size_t base = ((size_t)b * TT + (t0 + tid)) * 16 + blockIdx.y;
    cand1[base] = c1[tid];
    cand2[base] = c2[tid];
  }
}

// ---------------------------------------------------------------------------
// Merge 16 block candidates per token -> global top-2; write amaxIdx; flag
// near-ties (gap < GAP_THRESH) for f64 recheck.
// ---------------------------------------------------------------------------
__global__ __launch_bounds__(256) void merge_flag_kernel(
    const unsigned long long* __restrict__ cand1,
    const unsigned long long* __restrict__ cand2,
    unsigned long long* __restrict__ amaxIdx,
    unsigned* __restrict__ flagcount, unsigned* __restrict__ flaglist) {
  int bt = blockIdx.x * 256 + threadIdx.x;  // [0, B*T)
  unsigned long long b1 = 0ULL, b2 = 0ULL;
#pragma unroll
  for (int nb = 0; nb < 16; ++nb) {
    unsigned long long x = cand1[(size_t)bt * 16 + nb];
    if (x > b1) { b2 = b1; b1 = x; } else if (x > b2) b2 = x;
    unsigned long long y = cand2[(size_t)bt * 16 + nb];
    if (y > b2) { if (y > b1) { b2 = b1; b1 = y; } else b2 = y; }
  }
  amaxIdx[bt] = b1;
  float g = fdec((unsigned)(b1 >> 32)) - fdec((unsigned)(b2 >> 32));
  if (g < GAP_THRESH) {
    unsigned p = atomicAdd(flagcount, 1u);
    flaglist[p] = (unsigned)bt;
  }
}

// ---------------------------------------------------------------------------
// f64 recheck of flagged tokens: recompute sim[t, all n] from f32 q/k with
// f64 accumulation; overwrite amaxIdx[bt]. Fixed grid, strided over flags.
// ---------------------------------------------------------------------------
__global__ __launch_bounds__(256) void recheck_kernel(
    const float* __restrict__ q, const float* __restrict__ k,
    const unsigned* __restrict__ flagcount, const unsigned* __restrict__ flaglist,
    unsigned long long* __restrict__ amaxIdx) {
  __shared__ float klds[CC];
  __shared__ unsigned long long best;
  const unsigned cnt = *flagcount;
  for (unsigned fi = blockIdx.x; fi < cnt; fi += gridDim.x) {
    unsigned bt = flaglist[fi];
    int b = bt >> 11;
    int t = bt & (TT - 1);
    for (int c = threadIdx.x; c < CC; c += 256)
      klds[c] = k[((size_t)b * TT + t) * CC + c];
    if (threadIdx.x == 0) best = 0ULL;
    __syncthreads();

    const float* qb = q + (size_t)b * NNODE * CC;
    const float* q0 = qb + (size_t)(threadIdx.x) * CC;
    const float* q1 = qb + (size_t)(threadIdx.x + 256) * CC;
    const float* q2 = qb + (size_t)(threadIdx.x + 512) * CC;
    const float* q3 = qb + (size_t)(threadIdx.x + 768) * CC;
    double a0 = 0, a1 = 0, a2 = 0, a3 = 0;
    for (int c = 0; c < CC; ++c) {
      double kc = (double)klds[c];
      a0 = fma((double)q0[c], kc, a0);
      a1 = fma((double)q1[c], kc, a1);
      a2 = fma((double)q2[c], kc, a2);
      a3 = fma((double)q3[c], kc, a3);
    }
    const double scl = 0.04419417382415922;
    unsigned long long m = 0ULL;
    double av[4] = {a0, a1, a2, a3};
#pragma unroll
    for (int r = 0; r < 4; ++r) {
      float v = (float)(av[r] * scl);
      unsigned long long pk =
          ((unsigned long long)fkey(v) << 32) | (unsigned)(threadIdx.x + r * 256);
      if (pk > m) m = pk;
    }
    atomicMax(&best, m);
    __syncthreads();
    if (threadIdx.x == 0) amaxIdx[bt] = best;
    __syncthreads();
  }
}

__global__ __launch_bounds__(256) void node_max_kernel(
    const unsigned long long* __restrict__ amaxIdx, unsigned* __restrict__ Mpack) {
  int i = blockIdx.x * 256 + threadIdx.x;  // [0, B*T)
  unsigned long long pk = amaxIdx[i];
  int b = i >> 11;
  unsigned w = (unsigned)pk;
  atomicMax(&Mpack[b * NNODE + w], (unsigned)(pk >> 32));
}

__global__ __launch_bounds__(256) void node_denom_kernel(
    const unsigned long long* __restrict__ amaxIdx, const unsigned* __restrict__ Mpack,
    float* __restrict__ D, float* __restrict__ att_val) {
  int i = blockIdx.x * 256 + threadIdx.x;
  unsigned long long pk = amaxIdx[i];
  int b = i >> 11;
  unsigned w = (unsigned)pk;
  float amaxf = fdec((unsigned)(pk >> 32));
  float Mf = fdec(Mpack[b * NNODE + w]);
  float e = expf(amaxf - Mf);
  att_val[i] = e;
  atomicAdd(&D[b * NNODE + w], e);
}

__global__ __launch_bounds__(256) void att_write_kernel(
    const unsigned long long* __restrict__ amaxIdx, const float* __restrict__ D,
    float* __restrict__ att_val, float* __restrict__ att_out) {
  int i = blockIdx.x * 256 + threadIdx.x;
  unsigned long long pk = amaxIdx[i];
  int b = i >> 11;
  int t = i & (TT - 1);
  unsigned w = (unsigned)pk;
  float a = att_val[i] / D[b * NNODE + w];
  att_val[i] = a;
  att_out[((size_t)b * NNODE + w) * TT + t] = a;
}

__global__ __launch_bounds__(256) void pv_scatter_kernel(
    const unsigned long long* __restrict__ amaxIdx, const float* __restrict__ att_val,
    const __hip_bfloat16* __restrict__ v, float* __restrict__ out0) {
  int bt = blockIdx.x;  // [0, B*T)
  int b = bt >> 11;
  float a = att_val[bt];
  unsigned w = (unsigned)amaxIdx[bt];
  const __hip_bfloat16* vr = v + (size_t)bt * CC;
  float* orow = out0 + ((size_t)b * NNODE + w) * CC;
  for (int c = threadIdx.x; c < CC; c += 256)
    atomicAdd(&orow[c], a * __bfloat162float(vr[c]));
}

extern "C" void kernel_launch(void* const* d_in, const int* in_sizes, int n_in,
                              void* d_out, int out_size, void* d_ws, size_t ws_size,
                              hipStream_t stream) {
  const float* x = (const float*)d_in[0];     // [B,T,C]  f32
  const float* Wq = (const float*)d_in[1];    // [N,T]
  const float* bq = (const float*)d_in[2];    // [N]
  const float* Wk = (const float*)d_in[3];    // [C,C]
  const float* Wv = (const float*)d_in[4];    // [C,C]
  const float* Wout = (const float*)d_in[5];  // [C,C]
  const float* bout = (const float*)d_in[6];  // [C]

  float* out = (float*)d_out;                      // [B,N,C] f32
  float* att_out = out + (size_t)BB * NNODE * CC;  // [B,N,T] f32

  // Workspace layout (f32 units), ~68.5 MB total.
  float* ws = (float*)d_ws;
  float* q = ws;                                // B*N*C f32 (reused as out0)
  float* kbuf = q + (size_t)BB * NNODE * CC;    // B*T*C f32
  __hip_bfloat16* vbuf = (__hip_bfloat16*)(kbuf + (size_t)BB * TT * CC);  // bf16
  unsigned long long* cand1 =
      (unsigned long long*)((unsigned*)vbuf + (size_t)BB * TT * CC / 2);  // B*T*16 u64
  unsigned long long* cand2 = cand1 + (size_t)BB * TT * 16;               // B*T*16 u64
  unsigned long long* amaxIdx = cand2 + (size_t)BB * TT * 16;             // B*T u64
  unsigned* Mpack = (unsigned*)(amaxIdx + (size_t)BB * TT);               // B*N u32
  float* D = (float*)(Mpack + (size_t)BB * NNODE);                        // B*N f32
  unsigned* flagcount = (unsigned*)(D + (size_t)BB * NNODE);              // 16 u32
  float* att_val = (float*)(flagcount + 16);                              // B*T f32
  unsigned* flaglist = (unsigned*)(att_val + (size_t)BB * TT);            // B*T u32
  float* out0 = q;

  dim3 blk(256);

  // Z1: zero Mpack | D | flagcount (contiguous)
  fill_zero<<<dim3(64), blk, 0, stream>>>(
      Mpack, (long long)BB * NNODE * 2 + 16);
  // Z2: zero att region of d_out (B*N*T f32)
  fill_zero<<<dim3(4096), blk, 0, stream>>>(
      (unsigned*)att_out, (long long)BB * NNODE * TT);

  // q[b,n,c] = sum_t Wq[n,t] x[b,t,c] + bq[n]  (f64 acc, staged-f64 LDS)
  gemm_f64_kernel<1, false><<<dim3(CC / 64, NNODE / 64, BB), blk, 0, stream>>>(
      Wq, x, q, bq, NNODE, CC, TT, TT, CC, CC,
      0LL, (long long)TT * CC, (long long)NNODE * CC, 1.0f);

  // k[b,t,d] = sum_c x[b,t,c] Wk[d,c]  (f64 acc, staged-f64 LDS)
  gemm_f64_kernel<0, true><<<dim3(CC / 64, TT / 64, BB), blk, 0, stream>>>(
      x, Wk, kbuf, nullptr, TT, CC, CC, CC, CC, CC,
      (long long)TT * CC, 0LL, (long long)TT * CC, 1.0f);

  // v[b,t,d] (f32 acc, bf16 store, value path)
  gemm_kernel<0, true, true><<<dim3(CC / 64, TT / 64, BB), blk, 0, stream>>>(
      x, Wv, vbuf, nullptr, TT, CC, CC, CC, CC, CC,
      (long long)TT * CC, 0LL, (long long)TT * CC, 1.0f);

  // sim in f32 + block-local top-2 candidates
  sim_top2_kernel<<<dim3(TT / 64, NNODE / 64, BB), blk, 0, stream>>>(
      q, kbuf, cand1, cand2);

  // merge candidates -> amaxIdx + near-tie flags
  merge_flag_kernel<<<dim3(BB * TT / 256), blk, 0, stream>>>(
      cand1, cand2, amaxIdx, flagcount, flaglist);

  // f64 recheck of flagged tokens (fixed grid, strided; graph-safe)
  recheck_kernel<<<dim3(2048), blk, 0, stream>>>(q, kbuf, flagcount, flaglist, amaxIdx);

  // zero out0 (aliases q; q is dead after recheck)
  fill_zero<<<dim3(2048), blk, 0, stream>>>((unsigned*)out0, (long long)BB * NNODE * CC);

  node_max_kernel<<<dim3(BB * TT / 256), blk, 0, stream>>>(amaxIdx, Mpack);
  node_denom_kernel<<<dim3(BB * TT / 256), blk, 0, stream>>>(amaxIdx, Mpack, D, att_val);
  att_write_kernel<<<dim3(BB * TT / 256), blk, 0, stream>>>(amaxIdx, D, att_val, att_out);

  // sparse PV scatter: out0[b,w,c] += att * v[b,t,c]
  pv_scatter_kernel<<<dim3(BB * TT), blk, 0, stream>>>(amaxIdx, att_val, vbuf, out0);

  // out[b,n,d] = sum_c out0[b,n,c] Wout[d,c] + bout[d]  (f32 store)
  gemm_kernel<2, true, false><<<dim3(CC / 64, NNODE / 64, BB), blk, 0, stream>>>(
      out0, Wout, out, bout, NNODE, CC, CC, CC, CC, CC,
      (long long)NNODE * CC, 0LL, (long long)NNODE * CC, 1.0f);
}

// Round 7
// 1335.059 us; speedup vs baseline: 1.1898x; 1.1898x over previous
//
#include <hip/hip_runtime.h>
#include <hip/hip_bf16.h>
#include <cfloat>

// Problem constants
#define BB 8
#define TT 2048
#define CC 512
#define NNODE 1024

#define GAP_MARGIN 1e-3f  // screening margin (~33x f32-chain decision noise)
#define TPG 4             // flagged tokens per recheck group
#define MAXC 7            // max rival candidates per flagged token

// ---------------------------------------------------------------------------
// Order-preserving f32 <-> u32 key
// ---------------------------------------------------------------------------
__device__ __forceinline__ unsigned fkey(float v) {
  unsigned u = __float_as_uint(v);
  return (u & 0x80000000u) ? ~u : (u | 0x80000000u);
}
__device__ __forceinline__ float fdec(unsigned k) {
  unsigned u = (k & 0x80000000u) ? (k & 0x7FFFFFFFu) : ~k;
  return __uint_as_float(u);
}

// ---------------------------------------------------------------------------
// f32 tiled GEMM: C[m,n] = alpha*sum_k A[m,k]*B(k,n) (+bias)
// 64x64 tile, BK=16, 256 threads, 4x4 microtile.
// ---------------------------------------------------------------------------
template <int BIAS_MODE, bool TRANS_B, bool OUT_BF16>
__global__ __launch_bounds__(256) void gemm_kernel(
    const float* __restrict__ A, const float* __restrict__ Bm,
    void* __restrict__ Cp, const float* __restrict__ bias,
    int M, int N, int K, int lda, int ldb, int ldc,
    long long strideA, long long strideB, long long strideC, float alpha) {
  __shared__ float As[16][65];
  __shared__ float Bs[16][65];

  const int b = blockIdx.z;
  A += (long long)b * strideA;
  Bm += (long long)b * strideB;

  const int m0 = blockIdx.y * 64;
  const int n0 = blockIdx.x * 64;
  const int tid = threadIdx.x;
  const int tx = tid & 15;
  const int ty = tid >> 4;

  float acc[4][4] = {};

  for (int k0 = 0; k0 < K; k0 += 16) {
#pragma unroll
    for (int i = 0; i < 4; ++i) {
      int idx = tid + i * 256;
      int am = idx >> 4, ak = idx & 15;
      As[ak][am] = A[(long long)(m0 + am) * lda + (k0 + ak)];
    }
    if (!TRANS_B) {
#pragma unroll
      for (int i = 0; i < 4; ++i) {
        int idx = tid + i * 256;
        int bn = idx & 63, bk = idx >> 6;
        Bs[bk][bn] = Bm[(long long)(k0 + bk) * ldb + (n0 + bn)];
      }
    } else {
#pragma unroll
      for (int i = 0; i < 4; ++i) {
        int idx = tid + i * 256;
        int bk = idx & 15, bn = idx >> 4;
        Bs[bk][bn] = Bm[(long long)(n0 + bn) * ldb + (k0 + bk)];
      }
    }
    __syncthreads();

#pragma unroll
    for (int k = 0; k < 16; ++k) {
      float a[4], bb[4];
#pragma unroll
      for (int i = 0; i < 4; ++i) a[i] = As[k][ty + i * 16];
#pragma unroll
      for (int j = 0; j < 4; ++j) bb[j] = Bs[k][tx + j * 16];
#pragma unroll
      for (int i = 0; i < 4; ++i)
#pragma unroll
        for (int j = 0; j < 4; ++j) acc[i][j] = fmaf(a[i], bb[j], acc[i][j]);
    }
    __syncthreads();
  }

#pragma unroll
  for (int i = 0; i < 4; ++i) {
    int m = m0 + ty + i * 16;
#pragma unroll
    for (int j = 0; j < 4; ++j) {
      int n = n0 + tx + j * 16;
      float v = acc[i][j] * alpha;
      if (BIAS_MODE == 1) v += bias[m];
      if (BIAS_MODE == 2) v += bias[n];
      long long off = strideC * b + (long long)m * ldc + n;
      if (OUT_BF16)
        ((__hip_bfloat16*)Cp)[off] = __float2bfloat16(v);
      else
        ((float*)Cp)[off] = v;
    }
  }
}

// ---------------------------------------------------------------------------
// Fused k (f32) + v (bf16) projection: stages x tile once, two B tiles.
// k[t,d] = sum_c x[t,c] Wk[d,c] ; v[t,d] = sum_c x[t,c] Wv[d,c]
// ---------------------------------------------------------------------------
__global__ __launch_bounds__(256) void kv_gemm_kernel(
    const float* __restrict__ x, const float* __restrict__ Wk,
    const float* __restrict__ Wv, float* __restrict__ kout,
    __hip_bfloat16* __restrict__ vout) {
  __shared__ float As[16][65];
  __shared__ float Bk[16][65];
  __shared__ float Bv[16][65];

  const int b = blockIdx.z;
  const float* A = x + (size_t)b * TT * CC;
  const int m0 = blockIdx.y * 64;  // token rows
  const int n0 = blockIdx.x * 64;  // out dim
  const int tid = threadIdx.x;
  const int tx = tid & 15;
  const int ty = tid >> 4;

  float acck[4][4] = {};
  float accv[4][4] = {};

  for (int k0 = 0; k0 < CC; k0 += 16) {
#pragma unroll
    for (int i = 0; i < 4; ++i) {
      int idx = tid + i * 256;
      int am = idx >> 4, ak = idx & 15;
      As[ak][am] = A[(size_t)(m0 + am) * CC + (k0 + ak)];
    }
#pragma unroll
    for (int i = 0; i < 4; ++i) {
      int idx = tid + i * 256;
      int bk = idx & 15, bn = idx >> 4;
      Bk[bk][bn] = Wk[(size_t)(n0 + bn) * CC + (k0 + bk)];
      Bv[bk][bn] = Wv[(size_t)(n0 + bn) * CC + (k0 + bk)];
    }
    __syncthreads();

#pragma unroll
    for (int k = 0; k < 16; ++k) {
      float a[4], bk4[4], bv4[4];
#pragma unroll
      for (int i = 0; i < 4; ++i) a[i] = As[k][ty + i * 16];
#pragma unroll
      for (int j = 0; j < 4; ++j) { bk4[j] = Bk[k][tx + j * 16]; bv4[j] = Bv[k][tx + j * 16]; }
#pragma unroll
      for (int i = 0; i < 4; ++i)
#pragma unroll
        for (int j = 0; j < 4; ++j) {
          acck[i][j] = fmaf(a[i], bk4[j], acck[i][j]);
          accv[i][j] = fmaf(a[i], bv4[j], accv[i][j]);
        }
    }
    __syncthreads();
  }

#pragma unroll
  for (int i = 0; i < 4; ++i) {
    int m = m0 + ty + i * 16;
#pragma unroll
    for (int j = 0; j < 4; ++j) {
      int n = n0 + tx + j * 16;
      size_t off = ((size_t)b * TT + m) * CC + n;
      kout[off] = acck[i][j];
      vout[off] = __float2bfloat16(accv[i][j]);
    }
  }
}

__global__ __launch_bounds__(256) void fill_zero(unsigned* __restrict__ p, long long n) {
  long long i = (long long)blockIdx.x * 256 + threadIdx.x;
  long long stride = (long long)gridDim.x * 256;
  for (; i < n; i += stride) p[i] = 0u;
}

// ---------------------------------------------------------------------------
// sim in f32 + per-block per-token top-3 candidates (packed (fkey<<32)|node).
// ---------------------------------------------------------------------------
__global__ __launch_bounds__(256) void sim_top3_kernel(
    const float* __restrict__ q, const float* __restrict__ k,
    unsigned long long* __restrict__ cand1, unsigned long long* __restrict__ cand2,
    unsigned long long* __restrict__ cand3) {
  __shared__ float As[16][65];  // q tile: [kk][node]
  __shared__ float Bs[16][65];  // k tile: [kk][token]
  __shared__ unsigned long long c1[64], c2[64], c3[64];

  const int b = blockIdx.z;
  const float* A = q + (size_t)b * NNODE * CC;
  const float* Bm = k + (size_t)b * TT * CC;
  const int n0 = blockIdx.y * 64;
  const int t0 = blockIdx.x * 64;
  const int tid = threadIdx.x;
  const int tx = tid & 15;
  const int ty = tid >> 4;

  float acc[4][4] = {};

  for (int k0 = 0; k0 < CC; k0 += 16) {
#pragma unroll
    for (int i = 0; i < 4; ++i) {
      int idx = tid + i * 256;
      int am = idx >> 4, ak = idx & 15;
      As[ak][am] = A[(size_t)(n0 + am) * CC + (k0 + ak)];
    }
#pragma unroll
    for (int i = 0; i < 4; ++i) {
      int idx = tid + i * 256;
      int bk = idx & 15, bn = idx >> 4;
      Bs[bk][bn] = Bm[(size_t)(t0 + bn) * CC + (k0 + bk)];
    }
    __syncthreads();
#pragma unroll
    for (int kk = 0; kk < 16; ++kk) {
      float a[4], bb[4];
#pragma unroll
      for (int i = 0; i < 4; ++i) a[i] = As[kk][ty + i * 16];
#pragma unroll
      for (int j = 0; j < 4; ++j) bb[j] = Bs[kk][tx + j * 16];
#pragma unroll
      for (int i = 0; i < 4; ++i)
#pragma unroll
        for (int j = 0; j < 4; ++j) acc[i][j] = fmaf(a[i], bb[j], acc[i][j]);
    }
    __syncthreads();
  }

  if (tid < 64) { c1[tid] = 0ULL; c2[tid] = 0ULL; c3[tid] = 0ULL; }
  __syncthreads();

  const float scl = 0.04419417382415922f;
  unsigned long long pk[4][4];
#pragma unroll
  for (int j = 0; j < 4; ++j) {
    int col = tx + j * 16;
#pragma unroll
    for (int i = 0; i < 4; ++i) {
      float v = acc[i][j] * scl;
      pk[i][j] = ((unsigned long long)fkey(v) << 32) | (unsigned)(n0 + ty + i * 16);
    }
    unsigned long long m = pk[0][j];
#pragma unroll
    for (int i = 1; i < 4; ++i) m = (pk[i][j] > m) ? pk[i][j] : m;
    atomicMax(&c1[col], m);
  }
  __syncthreads();
#pragma unroll
  for (int j = 0; j < 4; ++j) {
    int col = tx + j * 16;
    unsigned w1 = (unsigned)c1[col];
    unsigned long long m = 0ULL;
#pragma unroll
    for (int i = 0; i < 4; ++i)
      if ((unsigned)pk[i][j] != w1 && pk[i][j] > m) m = pk[i][j];
    if (m) atomicMax(&c2[col], m);
  }
  __syncthreads();
#pragma unroll
  for (int j = 0; j < 4; ++j) {
    int col = tx + j * 16;
    unsigned w1 = (unsigned)c1[col];
    unsigned w2 = (unsigned)c2[col];
    unsigned long long m = 0ULL;
#pragma unroll
    for (int i = 0; i < 4; ++i) {
      unsigned nd = (unsigned)pk[i][j];
      if (nd != w1 && nd != w2 && pk[i][j] > m) m = pk[i][j];
    }
    if (m) atomicMax(&c3[col], m);
  }
  __syncthreads();
  if (tid < 64) {
    size_t base = ((size_t)b * TT + (t0 + tid)) * 16 + blockIdx.y;
    cand1[base] = c1[tid];
    cand2[base] = c2[tid];
    cand3[base] = c3[tid];
  }
}

// ---------------------------------------------------------------------------
// Merge 16x(top-3) -> global top1 + rival candidates within GAP_MARGIN.
// Flagged tokens go to per-batch lists for f64 recheck.
// ---------------------------------------------------------------------------
__global__ __launch_bounds__(256) void merge_flag_kernel(
    const unsigned long long* __restrict__ cand1,
    const unsigned long long* __restrict__ cand2,
    const unsigned long long* __restrict__ cand3,
    unsigned long long* __restrict__ amaxIdx,
    unsigned* __restrict__ counts, unsigned* __restrict__ flaglist,
    unsigned* __restrict__ clist) {
  int bt = blockIdx.x * 256 + threadIdx.x;  // [0, B*T)
  int b = bt >> 11;
  unsigned long long best = 0ULL;
#pragma unroll
  for (int nb = 0; nb < 16; ++nb) {
    unsigned long long v = cand1[(size_t)bt * 16 + nb];
    if (v > best) best = v;
  }
  amaxIdx[bt] = best;
  float v1 = fdec((unsigned)(best >> 32));
  float thr = v1 - GAP_MARGIN;
  unsigned bestnode = (unsigned)best;

  unsigned nodes[MAXC];
  int cnt = 0;
#pragma unroll
  for (int nb = 0; nb < 16; ++nb) {
    unsigned long long cs[3] = {cand1[(size_t)bt * 16 + nb], cand2[(size_t)bt * 16 + nb],
                                cand3[(size_t)bt * 16 + nb]};
#pragma unroll
    for (int s = 0; s < 3; ++s) {
      float v = fdec((unsigned)(cs[s] >> 32));
      unsigned nd = (unsigned)cs[s];
      if (v >= thr && nd != bestnode && cnt < MAXC) nodes[cnt++] = nd;
    }
  }
  if (cnt > 0) {
    unsigned p = atomicAdd(&counts[b], 1u);
    flaglist[b * TT + p] = (unsigned)bt;
    clist[(size_t)bt * 8] = (unsigned)(cnt + 1);
    clist[(size_t)bt * 8 + 1] = bestnode;
    for (int i = 0; i < cnt; ++i) clist[(size_t)bt * 8 + 2 + i] = nodes[i];
  }
}

// ---------------------------------------------------------------------------
// Exact f64 recheck of flagged tokens, recomputed from x:
//   k64 = f64(x_t . Wk^T row) ; z = x[b] . k64 (f64 acc, f32 stored);
//   sim64(n) = Wq[n,:].z + bq[n]*sum(k64)  -- candidates only.
// Groups of TPG tokens share the x[b] streaming in the z phase.
// ---------------------------------------------------------------------------
__global__ __launch_bounds__(256) void recheck_kernel(
    const float* __restrict__ x, const float* __restrict__ Wq,
    const float* __restrict__ bq, const float* __restrict__ Wk,
    const unsigned* __restrict__ counts, const unsigned* __restrict__ flaglist,
    const unsigned* __restrict__ clist, unsigned long long* __restrict__ amaxIdx) {
  __shared__ float xs[TPG][CC];     // 8KB
  __shared__ double k64[TPG][CC];   // 16KB
  __shared__ float zs[TPG][TT];     // 32KB
  __shared__ double red[4];
  __shared__ double ssum[TPG];

  const int b = blockIdx.y;
  const unsigned cnt = counts[b];
  const int tid = threadIdx.x;
  const float* xb = x + (size_t)b * TT * CC;

  for (unsigned base = blockIdx.x * TPG; base < cnt; base += gridDim.x * TPG) {
    const int nt = min((unsigned)TPG, cnt - base);
    // load x rows of the flagged tokens (zero-pad unused slots)
    for (int j = 0; j < TPG; ++j) {
      if (j < nt) {
        unsigned bt = flaglist[b * TT + base + j];
        int t = bt & (TT - 1);
        for (int c = tid; c < CC; c += 256) xs[j][c] = xb[(size_t)t * CC + c];
      } else {
        for (int c = tid; c < CC; c += 256) xs[j][c] = 0.f;
      }
    }
    __syncthreads();
    // k64 rows (f64 from x): thread d, d+256
    for (int j = 0; j < TPG; ++j)
      for (int d = tid; d < CC; d += 256) {
        const float* wr = Wk + (size_t)d * CC;
        double a = 0.0;
        for (int c = 0; c < CC; ++c) a = fma((double)xs[j][c], (double)wr[c], a);
        k64[j][d] = a;
      }
    __syncthreads();
    // sum of k64 (for the bias term), one thread per token (cheap)
    if (tid < TPG) {
      double s = 0.0;
      for (int c = 0; c < CC; ++c) s += k64[tid][c];
      ssum[tid] = s;
    }
    // z[t'] = x[b,t',:] . k64  (f64 acc, f32 store); shares x streaming
    for (int i = 0; i < TT / 256; ++i) {
      int tp = tid + i * 256;
      const float* xr = xb + (size_t)tp * CC;
      double a0 = 0, a1 = 0, a2 = 0, a3 = 0;
      for (int c = 0; c < CC; ++c) {
        double xv = (double)xr[c];
        a0 = fma(xv, k64[0][c], a0);
        a1 = fma(xv, k64[1][c], a1);
        a2 = fma(xv, k64[2][c], a2);
        a3 = fma(xv, k64[3][c], a3);
      }
      zs[0][tp] = (float)a0; zs[1][tp] = (float)a1;
      zs[2][tp] = (float)a2; zs[3][tp] = (float)a3;
    }
    __syncthreads();
    // candidate dots: sim64(n) = Wq[n,:].z + bq[n]*ssum
    const double scl = 0.04419417382415922;
    for (int j = 0; j < nt; ++j) {
      unsigned bt = flaglist[b * TT + base + j];
      unsigned nc = clist[(size_t)bt * 8];
      unsigned long long bestpk = 0ULL;
      double bestv = -1e300;
      for (unsigned ci = 0; ci < nc; ++ci) {
        unsigned n = clist[(size_t)bt * 8 + 1 + ci];
        const float* wq = Wq + (size_t)n * TT;
        double a = 0.0;
        for (int i = 0; i < TT / 256; ++i) {
          int tp = tid + i * 256;
          a = fma((double)wq[tp], (double)zs[j][tp], a);
        }
#pragma unroll
        for (int off = 32; off > 0; off >>= 1) a += __shfl_down(a, off, 64);
        if ((tid & 63) == 0) red[tid >> 6] = a;
        __syncthreads();
        if (tid == 0) {
          double s = (red[0] + red[1] + red[2] + red[3]) + (double)bq[n] * ssum[j];
          if (s > bestv) {
            bestv = s;
            bestpk = ((unsigned long long)fkey((float)(s * scl)) << 32) | n;
          }
        }
        __syncthreads();
      }
      if (tid == 0) amaxIdx[bt] = bestpk;
      __syncthreads();
    }
  }
}

__global__ __launch_bounds__(256) void node_max_kernel(
    const unsigned long long* __restrict__ amaxIdx, unsigned* __restrict__ Mpack) {
  int i = blockIdx.x * 256 + threadIdx.x;  // [0, B*T)
  unsigned long long pk = amaxIdx[i];
  int b = i >> 11;
  unsigned w = (unsigned)pk;
  atomicMax(&Mpack[b * NNODE + w], (unsigned)(pk >> 32));
}

__global__ __launch_bounds__(256) void node_denom_kernel(
    const unsigned long long* __restrict__ amaxIdx, const unsigned* __restrict__ Mpack,
    float* __restrict__ D, float* __restrict__ att_val) {
  int i = blockIdx.x * 256 + threadIdx.x;
  unsigned long long pk = amaxIdx[i];
  int b = i >> 11;
  unsigned w = (unsigned)pk;
  float amaxf = fdec((unsigned)(pk >> 32));
  float Mf = fdec(Mpack[b * NNODE + w]);
  float e = expf(amaxf - Mf);
  att_val[i] = e;
  atomicAdd(&D[b * NNODE + w], e);
}

__global__ __launch_bounds__(256) void att_write_kernel(
    const unsigned long long* __restrict__ amaxIdx, const float* __restrict__ D,
    float* __restrict__ att_val, float* __restrict__ att_out) {
  int i = blockIdx.x * 256 + threadIdx.x;
  unsigned long long pk = amaxIdx[i];
  int b = i >> 11;
  int t = i & (TT - 1);
  unsigned w = (unsigned)pk;
  float a = att_val[i] / D[b * NNODE + w];
  att_val[i] = a;
  att_out[((size_t)b * NNODE + w) * TT + t] = a;
}

__global__ __launch_bounds__(256) void pv_scatter_kernel(
    const unsigned long long* __restrict__ amaxIdx, const float* __restrict__ att_val,
    const __hip_bfloat16* __restrict__ v, float* __restrict__ out0) {
  int bt = blockIdx.x;  // [0, B*T)
  int b = bt >> 11;
  float a = att_val[bt];
  unsigned w = (unsigned)amaxIdx[bt];
  const __hip_bfloat16* vr = v + (size_t)bt * CC;
  float* orow = out0 + ((size_t)b * NNODE + w) * CC;
  for (int c = threadIdx.x; c < CC; c += 256)
    atomicAdd(&orow[c], a * __bfloat162float(vr[c]));
}

extern "C" void kernel_launch(void* const* d_in, const int* in_sizes, int n_in,
                              void* d_out, int out_size, void* d_ws, size_t ws_size,
                              hipStream_t stream) {
  const float* x = (const float*)d_in[0];     // [B,T,C]  f32
  const float* Wq = (const float*)d_in[1];    // [N,T]
  const float* bq = (const float*)d_in[2];    // [N]
  const float* Wk = (const float*)d_in[3];    // [C,C]
  const float* Wv = (const float*)d_in[4];    // [C,C]
  const float* Wout = (const float*)d_in[5];  // [C,C]
  const float* bout = (const float*)d_in[6];  // [C]

  float* out = (float*)d_out;                      // [B,N,C] f32
  float* att_out = out + (size_t)BB * NNODE * CC;  // [B,N,T] f32

  // Workspace layout (f32 word units), ~71 MB total.
  float* ws = (float*)d_ws;
  float* q = ws;                                // B*N*C f32 (reused as out0)
  float* kbuf = q + (size_t)BB * NNODE * CC;    // B*T*C f32
  __hip_bfloat16* vbuf = (__hip_bfloat16*)(kbuf + (size_t)BB * TT * CC);  // bf16
  unsigned long long* cand1 =
      (unsigned long long*)((unsigned*)vbuf + (size_t)BB * TT * CC / 2);  // B*T*16 u64
  unsigned long long* cand2 = cand1 + (size_t)BB * TT * 16;
  unsigned long long* cand3 = cand2 + (size_t)BB * TT * 16;
  unsigned long long* amaxIdx = cand3 + (size_t)BB * TT * 16;             // B*T u64
  unsigned* Mpack = (unsigned*)(amaxIdx + (size_t)BB * TT);               // B*N u32
  float* D = (float*)(Mpack + (size_t)BB * NNODE);                        // B*N f32
  unsigned* counts = (unsigned*)(D + (size_t)BB * NNODE);                 // 16 u32
  float* att_val = (float*)(counts + 16);                                 // B*T f32
  unsigned* flaglist = (unsigned*)(att_val + (size_t)BB * TT);            // B*T u32
  unsigned* clist = flaglist + (size_t)BB * TT;                           // B*T*8 u32
  float* out0 = q;

  dim3 blk(256);

  // Z1: zero Mpack | D | counts (contiguous)
  fill_zero<<<dim3(64), blk, 0, stream>>>(Mpack, (long long)BB * NNODE * 2 + 16);
  // Z2: zero att region of d_out
  fill_zero<<<dim3(4096), blk, 0, stream>>>((unsigned*)att_out,
                                            (long long)BB * NNODE * TT);

  // q[b,n,c] = sum_t Wq[n,t] x[b,t,c] + bq[n]  (f32, screening fidelity)
  gemm_kernel<1, false, false><<<dim3(CC / 64, NNODE / 64, BB), blk, 0, stream>>>(
      Wq, x, q, bq, NNODE, CC, TT, TT, CC, CC,
      0LL, (long long)TT * CC, (long long)NNODE * CC, 1.0f);

  // fused k (f32) + v (bf16)
  kv_gemm_kernel<<<dim3(CC / 64, TT / 64, BB), blk, 0, stream>>>(
      x, Wk, Wv, kbuf, vbuf);

  // sim f32 + per-block top-3 candidates
  sim_top3_kernel<<<dim3(TT / 64, NNODE / 64, BB), blk, 0, stream>>>(
      q, kbuf, cand1, cand2, cand3);

  // merge -> amaxIdx + flagged-token candidate lists
  merge_flag_kernel<<<dim3(BB * TT / 256), blk, 0, stream>>>(
      cand1, cand2, cand3, amaxIdx, counts, flaglist, clist);

  // exact f64 recheck of flagged tokens (from x; grid-stride, graph-safe)
  recheck_kernel<<<dim3(32, BB), blk, 0, stream>>>(
      x, Wq, bq, Wk, counts, flaglist, clist, amaxIdx);

  // zero out0 (aliases q; q dead after sim_top3)
  fill_zero<<<dim3(2048), blk, 0, stream>>>((unsigned*)out0, (long long)BB * NNODE * CC);

  node_max_kernel<<<dim3(BB * TT / 256), blk, 0, stream>>>(amaxIdx, Mpack);
  node_denom_kernel<<<dim3(BB * TT / 256), blk, 0, stream>>>(amaxIdx, Mpack, D, att_val);
  att_write_kernel<<<dim3(BB * TT / 256), blk, 0, stream>>>(amaxIdx, D, att_val, att_out);

  // sparse PV scatter: out0[b,w,c] += att * v[b,t,c]
  pv_scatter_kernel<<<dim3(BB * TT), blk, 0, stream>>>(amaxIdx, att_val, vbuf, out0);

  // out[b,n,d] = sum_c out0[b,n,c] Wout[d,c] + bout[d]  (f32 store)
  gemm_kernel<2, true, false><<<dim3(CC / 64, NNODE / 64, BB), blk, 0, stream>>>(
      out0, Wout, out, bout, NNODE, CC, CC, CC, CC, CC,
      (long long)NNODE * CC, 0LL, (long long)NNODE * CC, 1.0f);
}

// Round 8
// 738.661 us; speedup vs baseline: 2.1505x; 1.8074x over previous
//
#include <hip/hip_runtime.h>
#include <hip/hip_bf16.h>
#include <cfloat>

// Problem constants
#define BB 8
#define TT 2048
#define CC 512
#define NNODE 1024

#define GAP_MARGIN 1e-3f  // screening margin (~500x bf16-split-chain decision noise)
#define TPG 4             // flagged tokens per recheck group
#define MAXC 6            // max rival candidates per flagged token (fits 8-slot clist)

typedef float f32x4 __attribute__((ext_vector_type(4)));
typedef short bf16x8 __attribute__((ext_vector_type(8)));
typedef float float4v __attribute__((ext_vector_type(4)));

// ---------------------------------------------------------------------------
// Order-preserving f32 <-> u32 key
// ---------------------------------------------------------------------------
__device__ __forceinline__ unsigned fkey(float v) {
  unsigned u = __float_as_uint(v);
  return (u & 0x80000000u) ? ~u : (u | 0x80000000u);
}
__device__ __forceinline__ float fdec(unsigned k) {
  unsigned u = (k & 0x80000000u) ? (k & 0x7FFFFFFFu) : ~k;
  return __uint_as_float(u);
}

// bf16 round-to-nearest-even helpers (bit-level, no type issues)
__device__ __forceinline__ unsigned short bf16_rn(float f) {
  unsigned u = __float_as_uint(f);
  u += 0x7FFFu + ((u >> 16) & 1u);
  return (unsigned short)(u >> 16);
}
__device__ __forceinline__ float bf16_tof(unsigned short h) {
  return __uint_as_float(((unsigned)h) << 16);
}

// ---------------------------------------------------------------------------
// MFMA GEMM: C[m,n] = alpha*sum_k A[m,k]*B(k,n) (+bias), f32 in/out.
//   SPLIT: bf16-split (hh+hl+lh) for ~f32 fidelity; else plain bf16.
//   TRANS_B: B is [N][K] row-major; else [K][N] (transposed during staging).
// 128x128 tile, BK=32, 256 threads (4 waves, 2x2), 16 16x16x32 frags/wave.
// ---------------------------------------------------------------------------
template <bool SPLIT, bool TRANS_B, int BIAS_MODE>
__global__ __launch_bounds__(256) void mfma_gemm(
    const float* __restrict__ A, const float* __restrict__ Bm,
    float* __restrict__ Cp, const float* __restrict__ bias,
    int K, int lda, int ldb, int ldc,
    long long sA, long long sB, long long sC, float alpha) {
  __shared__ unsigned short Ah[128][40], Al[128][40], Bh[128][40], Bl[128][40];

  const int b = blockIdx.z;
  A += (long long)b * sA;
  Bm += (long long)b * sB;
  const int m0 = blockIdx.y * 128;
  const int n0 = blockIdx.x * 128;
  const int tid = threadIdx.x;
  const int l = tid & 63;
  const int wid = tid >> 6;
  const int wy = wid >> 1, wx = wid & 1;
  const int lrow = l & 15, lkb = (l >> 4) * 8;

  f32x4 acc[4][4] = {};

  for (int k0 = 0; k0 < K; k0 += 32) {
    {
      int r = tid >> 3, c = (tid & 7) * 4;
#pragma unroll
      for (int p = 0; p < 4; ++p, r += 32) {
        float4v v = *(const float4v*)(A + (long long)(m0 + r) * lda + k0 + c);
#pragma unroll
        for (int i = 0; i < 4; ++i) {
          unsigned short h = bf16_rn(v[i]);
          Ah[r][c + i] = h;
          if (SPLIT) Al[r][c + i] = bf16_rn(v[i] - bf16_tof(h));
        }
      }
    }
    if (TRANS_B) {
      int r = tid >> 3, c = (tid & 7) * 4;
#pragma unroll
      for (int p = 0; p < 4; ++p, r += 32) {
        float4v v = *(const float4v*)(Bm + (long long)(n0 + r) * ldb + k0 + c);
#pragma unroll
        for (int i = 0; i < 4; ++i) {
          unsigned short h = bf16_rn(v[i]);
          Bh[r][c + i] = h;
          if (SPLIT) Bl[r][c + i] = bf16_rn(v[i] - bf16_tof(h));
        }
      }
    } else {
      int kk = tid >> 5, c = (tid & 31) * 4;
#pragma unroll
      for (int p = 0; p < 4; ++p, kk += 8) {
        float4v v = *(const float4v*)(Bm + (long long)(k0 + kk) * ldb + n0 + c);
#pragma unroll
        for (int i = 0; i < 4; ++i) {
          unsigned short h = bf16_rn(v[i]);
          Bh[c + i][kk] = h;
          if (SPLIT) Bl[c + i][kk] = bf16_rn(v[i] - bf16_tof(h));
        }
      }
    }
    __syncthreads();

    bf16x8 ah[4], bh[4], al[4], bl[4];
#pragma unroll
    for (int mf = 0; mf < 4; ++mf) {
      ah[mf] = *(const bf16x8*)&Ah[wy * 64 + mf * 16 + lrow][lkb];
      if (SPLIT) al[mf] = *(const bf16x8*)&Al[wy * 64 + mf * 16 + lrow][lkb];
    }
#pragma unroll
    for (int nf = 0; nf < 4; ++nf) {
      bh[nf] = *(const bf16x8*)&Bh[wx * 64 + nf * 16 + lrow][lkb];
      if (SPLIT) bl[nf] = *(const bf16x8*)&Bl[wx * 64 + nf * 16 + lrow][lkb];
    }
#pragma unroll
    for (int mf = 0; mf < 4; ++mf)
#pragma unroll
      for (int nf = 0; nf < 4; ++nf) {
        acc[mf][nf] =
            __builtin_amdgcn_mfma_f32_16x16x32_bf16(ah[mf], bh[nf], acc[mf][nf], 0, 0, 0);
        if (SPLIT) {
          acc[mf][nf] =
              __builtin_amdgcn_mfma_f32_16x16x32_bf16(ah[mf], bl[nf], acc[mf][nf], 0, 0, 0);
          acc[mf][nf] =
              __builtin_amdgcn_mfma_f32_16x16x32_bf16(al[mf], bh[nf], acc[mf][nf], 0, 0, 0);
        }
      }
    __syncthreads();
  }

#pragma unroll
  for (int mf = 0; mf < 4; ++mf)
#pragma unroll
    for (int r = 0; r < 4; ++r) {
      int m = m0 + wy * 64 + mf * 16 + (l >> 4) * 4 + r;
#pragma unroll
      for (int nf = 0; nf < 4; ++nf) {
        int n = n0 + wx * 64 + nf * 16 + lrow;
        float v = acc[mf][nf][r] * alpha;
        if (BIAS_MODE == 1) v += bias[m];
        if (BIAS_MODE == 2) v += bias[n];
        Cp[sC * b + (long long)m * ldc + n] = v;
      }
    }
}

// ---------------------------------------------------------------------------
// Fused k (bf16-split, f32 out) + v (plain bf16, bf16 out) projection.
// ---------------------------------------------------------------------------
__global__ __launch_bounds__(256) void mfma_kv(
    const float* __restrict__ x, const float* __restrict__ Wk,
    const float* __restrict__ Wv, float* __restrict__ kout,
    unsigned short* __restrict__ vout) {
  __shared__ unsigned short Ah[128][40], Al[128][40], Bkh[128][40], Bkl[128][40],
      Bvh[128][40];

  const int b = blockIdx.z;
  const float* A = x + (size_t)b * TT * CC;
  const int m0 = blockIdx.y * 128;  // tokens
  const int n0 = blockIdx.x * 128;  // out dim
  const int tid = threadIdx.x;
  const int l = tid & 63;
  const int wid = tid >> 6;
  const int wy = wid >> 1, wx = wid & 1;
  const int lrow = l & 15, lkb = (l >> 4) * 8;

  f32x4 acck[4][4] = {}, accv[4][4] = {};

  for (int k0 = 0; k0 < CC; k0 += 32) {
    {
      int r = tid >> 3, c = (tid & 7) * 4;
#pragma unroll
      for (int p = 0; p < 4; ++p, r += 32) {
        float4v v = *(const float4v*)(A + (size_t)(m0 + r) * CC + k0 + c);
        float4v wk = *(const float4v*)(Wk + (size_t)(n0 + r) * CC + k0 + c);
        float4v wv = *(const float4v*)(Wv + (size_t)(n0 + r) * CC + k0 + c);
#pragma unroll
        for (int i = 0; i < 4; ++i) {
          unsigned short h = bf16_rn(v[i]);
          Ah[r][c + i] = h;
          Al[r][c + i] = bf16_rn(v[i] - bf16_tof(h));
          unsigned short hk = bf16_rn(wk[i]);
          Bkh[r][c + i] = hk;
          Bkl[r][c + i] = bf16_rn(wk[i] - bf16_tof(hk));
          Bvh[r][c + i] = bf16_rn(wv[i]);
        }
      }
    }
    __syncthreads();

    bf16x8 ah[4], al[4], bkh[4], bkl[4], bvh[4];
#pragma unroll
    for (int mf = 0; mf < 4; ++mf) {
      ah[mf] = *(const bf16x8*)&Ah[wy * 64 + mf * 16 + lrow][lkb];
      al[mf] = *(const bf16x8*)&Al[wy * 64 + mf * 16 + lrow][lkb];
    }
#pragma unroll
    for (int nf = 0; nf < 4; ++nf) {
      bkh[nf] = *(const bf16x8*)&Bkh[wx * 64 + nf * 16 + lrow][lkb];
      bkl[nf] = *(const bf16x8*)&Bkl[wx * 64 + nf * 16 + lrow][lkb];
      bvh[nf] = *(const bf16x8*)&Bvh[wx * 64 + nf * 16 + lrow][lkb];
    }
#pragma unroll
    for (int mf = 0; mf < 4; ++mf)
#pragma unroll
      for (int nf = 0; nf < 4; ++nf) {
        acck[mf][nf] =
            __builtin_amdgcn_mfma_f32_16x16x32_bf16(ah[mf], bkh[nf], acck[mf][nf], 0, 0, 0);
        acck[mf][nf] =
            __builtin_amdgcn_mfma_f32_16x16x32_bf16(ah[mf], bkl[nf], acck[mf][nf], 0, 0, 0);
        acck[mf][nf] =
            __builtin_amdgcn_mfma_f32_16x16x32_bf16(al[mf], bkh[nf], acck[mf][nf], 0, 0, 0);
        accv[mf][nf] =
            __builtin_amdgcn_mfma_f32_16x16x32_bf16(ah[mf], bvh[nf], accv[mf][nf], 0, 0, 0);
      }
    __syncthreads();
  }

#pragma unroll
  for (int mf = 0; mf < 4; ++mf)
#pragma unroll
    for (int r = 0; r < 4; ++r) {
      int m = m0 + wy * 64 + mf * 16 + (l >> 4) * 4 + r;
#pragma unroll
      for (int nf = 0; nf < 4; ++nf) {
        int n = n0 + wx * 64 + nf * 16 + lrow;
        size_t off = ((size_t)b * TT + m) * CC + n;
        kout[off] = acck[mf][nf][r];
        vout[off] = bf16_rn(accv[mf][nf][r]);
      }
    }
}

// ---------------------------------------------------------------------------
// sim (bf16-split MFMA, no store) + per-block per-token top-3 candidates.
// ---------------------------------------------------------------------------
__global__ __launch_bounds__(256) void mfma_sim_top3(
    const float* __restrict__ q, const float* __restrict__ kb,
    unsigned long long* __restrict__ cand1, unsigned long long* __restrict__ cand2,
    unsigned long long* __restrict__ cand3) {
  __shared__ unsigned short Ah[128][40], Al[128][40], Bh[128][40], Bl[128][40];
  __shared__ unsigned long long c1[128], c2[128], c3[128];

  const int b = blockIdx.z;
  const float* A = q + (size_t)b * NNODE * CC;
  const float* Bm = kb + (size_t)b * TT * CC;
  const int n0 = blockIdx.y * 128;  // nodes
  const int t0 = blockIdx.x * 128;  // tokens
  const int tid = threadIdx.x;
  const int l = tid & 63;
  const int wid = tid >> 6;
  const int wy = wid >> 1, wx = wid & 1;
  const int lrow = l & 15, lkb = (l >> 4) * 8;

  if (tid < 128) { c1[tid] = 0ULL; c2[tid] = 0ULL; c3[tid] = 0ULL; }

  f32x4 acc[4][4] = {};

  for (int k0 = 0; k0 < CC; k0 += 32) {
    {
      int r = tid >> 3, c = (tid & 7) * 4;
#pragma unroll
      for (int p = 0; p < 4; ++p, r += 32) {
        float4v v = *(const float4v*)(A + (size_t)(n0 + r) * CC + k0 + c);
        float4v w = *(const float4v*)(Bm + (size_t)(t0 + r) * CC + k0 + c);
#pragma unroll
        for (int i = 0; i < 4; ++i) {
          unsigned short h = bf16_rn(v[i]);
          Ah[r][c + i] = h;
          Al[r][c + i] = bf16_rn(v[i] - bf16_tof(h));
          unsigned short hb = bf16_rn(w[i]);
          Bh[r][c + i] = hb;
          Bl[r][c + i] = bf16_rn(w[i] - bf16_tof(hb));
        }
      }
    }
    __syncthreads();

    bf16x8 ah[4], al[4], bh[4], bl[4];
#pragma unroll
    for (int mf = 0; mf < 4; ++mf) {
      ah[mf] = *(const bf16x8*)&Ah[wy * 64 + mf * 16 + lrow][lkb];
      al[mf] = *(const bf16x8*)&Al[wy * 64 + mf * 16 + lrow][lkb];
    }
#pragma unroll
    for (int nf = 0; nf < 4; ++nf) {
      bh[nf] = *(const bf16x8*)&Bh[wx * 64 + nf * 16 + lrow][lkb];
      bl[nf] = *(const bf16x8*)&Bl[wx * 64 + nf * 16 + lrow][lkb];
    }
#pragma unroll
    for (int mf = 0; mf < 4; ++mf)
#pragma unroll
      for (int nf = 0; nf < 4; ++nf) {
        acc[mf][nf] =
            __builtin_amdgcn_mfma_f32_16x16x32_bf16(ah[mf], bh[nf], acc[mf][nf], 0, 0, 0);
        acc[mf][nf] =
            __builtin_amdgcn_mfma_f32_16x16x32_bf16(ah[mf], bl[nf], acc[mf][nf], 0, 0, 0);
        acc[mf][nf] =
            __builtin_amdgcn_mfma_f32_16x16x32_bf16(al[mf], bh[nf], acc[mf][nf], 0, 0, 0);
      }
    __syncthreads();
  }

  const float scl = 0.04419417382415922f;
  // phase 1: local best -> c1
#pragma unroll
  for (int nf = 0; nf < 4; ++nf) {
    int tcol = wx * 64 + nf * 16 + lrow;
    unsigned long long m = 0ULL;
#pragma unroll
    for (int mf = 0; mf < 4; ++mf)
#pragma unroll
      for (int r = 0; r < 4; ++r) {
        unsigned node = (unsigned)(n0 + wy * 64 + mf * 16 + (l >> 4) * 4 + r);
        unsigned long long pk =
            ((unsigned long long)fkey(acc[mf][nf][r] * scl) << 32) | node;
        if (pk > m) m = pk;
      }
    atomicMax(&c1[tcol], m);
  }
  __syncthreads();
  // phase 2: exclude w1 -> c2
#pragma unroll
  for (int nf = 0; nf < 4; ++nf) {
    int tcol = wx * 64 + nf * 16 + lrow;
    unsigned w1 = (unsigned)c1[tcol];
    unsigned long long m = 0ULL;
#pragma unroll
    for (int mf = 0; mf < 4; ++mf)
#pragma unroll
      for (int r = 0; r < 4; ++r) {
        unsigned node = (unsigned)(n0 + wy * 64 + mf * 16 + (l >> 4) * 4 + r);
        if (node == w1) continue;
        unsigned long long pk =
            ((unsigned long long)fkey(acc[mf][nf][r] * scl) << 32) | node;
        if (pk > m) m = pk;
      }
    if (m) atomicMax(&c2[tcol], m);
  }
  __syncthreads();
  // phase 3: exclude w1,w2 -> c3
#pragma unroll
  for (int nf = 0; nf < 4; ++nf) {
    int tcol = wx * 64 + nf * 16 + lrow;
    unsigned w1 = (unsigned)c1[tcol];
    unsigned w2 = (unsigned)c2[tcol];
    unsigned long long m = 0ULL;
#pragma unroll
    for (int mf = 0; mf < 4; ++mf)
#pragma unroll
      for (int r = 0; r < 4; ++r) {
        unsigned node = (unsigned)(n0 + wy * 64 + mf * 16 + (l >> 4) * 4 + r);
        if (node == w1 || node == w2) continue;
        unsigned long long pk =
            ((unsigned long long)fkey(acc[mf][nf][r] * scl) << 32) | node;
        if (pk > m) m = pk;
      }
    if (m) atomicMax(&c3[tcol], m);
  }
  __syncthreads();
  if (tid < 128) {
    size_t base = ((size_t)b * TT + (t0 + tid)) * 8 + blockIdx.y;
    cand1[base] = c1[tid];
    cand2[base] = c2[tid];
    cand3[base] = c3[tid];
  }
}

__global__ __launch_bounds__(256) void fill_zero(unsigned* __restrict__ p, long long n) {
  long long i = (long long)blockIdx.x * 256 + threadIdx.x;
  long long stride = (long long)gridDim.x * 256;
  for (; i < n; i += stride) p[i] = 0u;
}

// ---------------------------------------------------------------------------
// Merge 8x(top-3) -> global top1 + rivals within GAP_MARGIN -> flag lists.
// ---------------------------------------------------------------------------
__global__ __launch_bounds__(256) void merge_flag_kernel(
    const unsigned long long* __restrict__ cand1,
    const unsigned long long* __restrict__ cand2,
    const unsigned long long* __restrict__ cand3,
    unsigned long long* __restrict__ amaxIdx,
    unsigned* __restrict__ counts, unsigned* __restrict__ flaglist,
    unsigned* __restrict__ clist) {
  int bt = blockIdx.x * 256 + threadIdx.x;  // [0, B*T)
  int b = bt >> 11;
  unsigned long long best = 0ULL;
#pragma unroll
  for (int nb = 0; nb < 8; ++nb) {
    unsigned long long v = cand1[(size_t)bt * 8 + nb];
    if (v > best) best = v;
  }
  amaxIdx[bt] = best;
  float v1 = fdec((unsigned)(best >> 32));
  float thr = v1 - GAP_MARGIN;
  unsigned bestnode = (unsigned)best;

  unsigned nodes[MAXC];
  int cnt = 0;
#pragma unroll
  for (int nb = 0; nb < 8; ++nb) {
    unsigned long long cs[3] = {cand1[(size_t)bt * 8 + nb], cand2[(size_t)bt * 8 + nb],
                                cand3[(size_t)bt * 8 + nb]};
#pragma unroll
    for (int s = 0; s < 3; ++s) {
      float v = fdec((unsigned)(cs[s] >> 32));
      unsigned nd = (unsigned)cs[s];
      if (v >= thr && nd != bestnode && cnt < MAXC) nodes[cnt++] = nd;
    }
  }
  if (cnt > 0) {
    unsigned p = atomicAdd(&counts[b], 1u);
    flaglist[b * TT + p] = (unsigned)bt;
    clist[(size_t)bt * 8] = (unsigned)(cnt + 1);
    clist[(size_t)bt * 8 + 1] = bestnode;
    for (int i = 0; i < cnt; ++i) clist[(size_t)bt * 8 + 2 + i] = nodes[i];
  }
}

// ---------------------------------------------------------------------------
// Exact f64 recheck of flagged tokens, recomputed from x.
// ---------------------------------------------------------------------------
__global__ __launch_bounds__(256) void recheck_kernel(
    const float* __restrict__ x, const float* __restrict__ Wq,
    const float* __restrict__ bq, const float* __restrict__ Wk,
    const unsigned* __restrict__ counts, const unsigned* __restrict__ flaglist,
    const unsigned* __restrict__ clist, unsigned long long* __restrict__ amaxIdx) {
  __shared__ float xs[TPG][CC];
  __shared__ double k64[TPG][CC];
  __shared__ float zs[TPG][TT];
  __shared__ double red[4];
  __shared__ double ssum[TPG];

  const int b = blockIdx.y;
  const unsigned cnt = counts[b];
  const int tid = threadIdx.x;
  const float* xb = x + (size_t)b * TT * CC;

  for (unsigned base = blockIdx.x * TPG; base < cnt; base += gridDim.x * TPG) {
    const int nt = min((unsigned)TPG, cnt - base);
    for (int j = 0; j < TPG; ++j) {
      if (j < nt) {
        unsigned bt = flaglist[b * TT + base + j];
        int t = bt & (TT - 1);
        for (int c = tid; c < CC; c += 256) xs[j][c] = xb[(size_t)t * CC + c];
      } else {
        for (int c = tid; c < CC; c += 256) xs[j][c] = 0.f;
      }
    }
    __syncthreads();
    for (int j = 0; j < TPG; ++j)
      for (int d = tid; d < CC; d += 256) {
        const float* wr = Wk + (size_t)d * CC;
        double a = 0.0;
        for (int c = 0; c < CC; ++c) a = fma((double)xs[j][c], (double)wr[c], a);
        k64[j][d] = a;
      }
    __syncthreads();
    if (tid < TPG) {
      double s = 0.0;
      for (int c = 0; c < CC; ++c) s += k64[tid][c];
      ssum[tid] = s;
    }
    for (int i = 0; i < TT / 256; ++i) {
      int tp = tid + i * 256;
      const float* xr = xb + (size_t)tp * CC;
      double a0 = 0, a1 = 0, a2 = 0, a3 = 0;
      for (int c = 0; c < CC; ++c) {
        double xv = (double)xr[c];
        a0 = fma(xv, k64[0][c], a0);
        a1 = fma(xv, k64[1][c], a1);
        a2 = fma(xv, k64[2][c], a2);
        a3 = fma(xv, k64[3][c], a3);
      }
      zs[0][tp] = (float)a0; zs[1][tp] = (float)a1;
      zs[2][tp] = (float)a2; zs[3][tp] = (float)a3;
    }
    __syncthreads();
    const double scl = 0.04419417382415922;
    for (int j = 0; j < nt; ++j) {
      unsigned bt = flaglist[b * TT + base + j];
      unsigned nc = clist[(size_t)bt * 8];
      unsigned long long bestpk = 0ULL;
      double bestv = -1e300;
      for (unsigned ci = 0; ci < nc; ++ci) {
        unsigned n = clist[(size_t)bt * 8 + 1 + ci];
        const float* wq = Wq + (size_t)n * TT;
        double a = 0.0;
        for (int i = 0; i < TT / 256; ++i) {
          int tp = tid + i * 256;
          a = fma((double)wq[tp], (double)zs[j][tp], a);
        }
#pragma unroll
        for (int off = 32; off > 0; off >>= 1) a += __shfl_down(a, off, 64);
        if ((tid & 63) == 0) red[tid >> 6] = a;
        __syncthreads();
        if (tid == 0) {
          double s = (red[0] + red[1] + red[2] + red[3]) + (double)bq[n] * ssum[j];
          if (s > bestv) {
            bestv = s;
            bestpk = ((unsigned long long)fkey((float)(s * scl)) << 32) | n;
          }
        }
        __syncthreads();
      }
      if (tid == 0) amaxIdx[bt] = bestpk;
      __syncthreads();
    }
  }
}

__global__ __launch_bounds__(256) void node_max_kernel(
    const unsigned long long* __restrict__ amaxIdx, unsigned* __restrict__ Mpack) {
  int i = blockIdx.x * 256 + threadIdx.x;
  unsigned long long pk = amaxIdx[i];
  int b = i >> 11;
  unsigned w = (unsigned)pk;
  atomicMax(&Mpack[b * NNODE + w], (unsigned)(pk >> 32));
}

__global__ __launch_bounds__(256) void node_denom_kernel(
    const unsigned long long* __restrict__ amaxIdx, const unsigned* __restrict__ Mpack,
    float* __restrict__ D, float* __restrict__ att_val) {
  int i = blockIdx.x * 256 + threadIdx.x;
  unsigned long long pk = amaxIdx[i];
  int b = i >> 11;
  unsigned w = (unsigned)pk;
  float amaxf = fdec((unsigned)(pk >> 32));
  float Mf = fdec(Mpack[b * NNODE + w]);
  float e = expf(amaxf - Mf);
  att_val[i] = e;
  atomicAdd(&D[b * NNODE + w], e);
}

__global__ __launch_bounds__(256) void att_write_kernel(
    const unsigned long long* __restrict__ amaxIdx, const float* __restrict__ D,
    float* __restrict__ att_val, float* __restrict__ att_out) {
  int i = blockIdx.x * 256 + threadIdx.x;
  unsigned long long pk = amaxIdx[i];
  int b = i >> 11;
  int t = i & (TT - 1);
  unsigned w = (unsigned)pk;
  float a = att_val[i] / D[b * NNODE + w];
  att_val[i] = a;
  att_out[((size_t)b * NNODE + w) * TT + t] = a;
}

__global__ __launch_bounds__(256) void pv_scatter_kernel(
    const unsigned long long* __restrict__ amaxIdx, const float* __restrict__ att_val,
    const unsigned short* __restrict__ v, float* __restrict__ out0) {
  int bt = blockIdx.x;  // [0, B*T)
  int b = bt >> 11;
  float a = att_val[bt];
  unsigned w = (unsigned)amaxIdx[bt];
  const unsigned short* vr = v + (size_t)bt * CC;
  float* orow = out0 + ((size_t)b * NNODE + w) * CC;
  for (int c = threadIdx.x; c < CC; c += 256)
    atomicAdd(&orow[c], a * bf16_tof(vr[c]));
}

extern "C" void kernel_launch(void* const* d_in, const int* in_sizes, int n_in,
                              void* d_out, int out_size, void* d_ws, size_t ws_size,
                              hipStream_t stream) {
  const float* x = (const float*)d_in[0];     // [B,T,C]  f32
  const float* Wq = (const float*)d_in[1];    // [N,T]
  const float* bq = (const float*)d_in[2];    // [N]
  const float* Wk = (const float*)d_in[3];    // [C,C]
  const float* Wv = (const float*)d_in[4];    // [C,C]
  const float* Wout = (const float*)d_in[5];  // [C,C]
  const float* bout = (const float*)d_in[6];  // [C]

  float* out = (float*)d_out;                      // [B,N,C] f32
  float* att_out = out + (size_t)BB * NNODE * CC;  // [B,N,T] f32

  // Workspace layout (f32 word units), ~71 MB total.
  float* ws = (float*)d_ws;
  float* q = ws;                                // B*N*C f32 (reused as out0)
  float* kbuf = q + (size_t)BB * NNODE * CC;    // B*T*C f32
  unsigned short* vbuf = (unsigned short*)(kbuf + (size_t)BB * TT * CC);  // bf16 bits
  unsigned long long* cand1 =
      (unsigned long long*)((unsigned*)vbuf + (size_t)BB * TT * CC / 2);  // B*T*8 u64
  unsigned long long* cand2 = cand1 + (size_t)BB * TT * 8;
  unsigned long long* cand3 = cand2 + (size_t)BB * TT * 8;
  unsigned long long* amaxIdx = cand3 + (size_t)BB * TT * 8;              // B*T u64
  unsigned* Mpack = (unsigned*)(amaxIdx + (size_t)BB * TT);               // B*N u32
  float* D = (float*)(Mpack + (size_t)BB * NNODE);                        // B*N f32
  unsigned* counts = (unsigned*)(D + (size_t)BB * NNODE);                 // 16 u32
  float* att_val = (float*)(counts + 16);                                 // B*T f32
  unsigned* flaglist = (unsigned*)(att_val + (size_t)BB * TT);            // B*T u32
  unsigned* clist = flaglist + (size_t)BB * TT;                           // B*T*8 u32
  float* out0 = q;

  dim3 blk(256);

  // Z1: zero Mpack | D | counts (contiguous)
  fill_zero<<<dim3(64), blk, 0, stream>>>(Mpack, (long long)BB * NNODE * 2 + 16);
  // Z2: zero att region of d_out
  fill_zero<<<dim3(4096), blk, 0, stream>>>((unsigned*)att_out,
                                            (long long)BB * NNODE * TT);

  // q[b,n,c] = sum_t Wq[n,t] x[b,t,c] + bq[n]  (bf16-split MFMA)
  mfma_gemm<true, false, 1><<<dim3(CC / 128, NNODE / 128, BB), blk, 0, stream>>>(
      Wq, x, q, bq, TT, TT, CC, CC, 0LL, (long long)TT * CC,
      (long long)NNODE * CC, 1.0f);

  // fused k (split, f32) + v (plain, bf16)
  mfma_kv<<<dim3(CC / 128, TT / 128, BB), blk, 0, stream>>>(x, Wk, Wv, kbuf, vbuf);

  // sim (split MFMA) + per-block top-3 candidates
  mfma_sim_top3<<<dim3(TT / 128, NNODE / 128, BB), blk, 0, stream>>>(
      q, kbuf, cand1, cand2, cand3);

  // merge -> amaxIdx + flagged-token candidate lists
  merge_flag_kernel<<<dim3(BB * TT / 256), blk, 0, stream>>>(
      cand1, cand2, cand3, amaxIdx, counts, flaglist, clist);

  // exact f64 recheck of flagged tokens
  recheck_kernel<<<dim3(32, BB), blk, 0, stream>>>(
      x, Wq, bq, Wk, counts, flaglist, clist, amaxIdx);

  // zero out0 (aliases q; q dead after sim)
  fill_zero<<<dim3(2048), blk, 0, stream>>>((unsigned*)out0, (long long)BB * NNODE * CC);

  node_max_kernel<<<dim3(BB * TT / 256), blk, 0, stream>>>(amaxIdx, Mpack);
  node_denom_kernel<<<dim3(BB * TT / 256), blk, 0, stream>>>(amaxIdx, Mpack, D, att_val);
  att_write_kernel<<<dim3(BB * TT / 256), blk, 0, stream>>>(amaxIdx, D, att_val, att_out);

  // sparse PV scatter: out0[b,w,c] += att * v[b,t,c]
  pv_scatter_kernel<<<dim3(BB * TT), blk, 0, stream>>>(amaxIdx, att_val, vbuf, out0);

  // out[b,n,d] = sum_c out0[b,n,c] Wout[d,c] + bout[d]  (plain MFMA, flattened M)
  mfma_gemm<false, true, 2><<<dim3(CC / 128, BB * NNODE / 128, 1), blk, 0, stream>>>(
      out0, Wout, out, bout, CC, CC, CC, CC, 0LL, 0LL, 0LL, 1.0f);
}